// Round 5
// baseline (460.505 us; speedup 1.0000x reference)
//
#include <hip/hip_runtime.h>
#include <stdint.h>

#define B_GRAPHS 256
#define NPER     512
#define EPER     4096
#define DDIM     64
#define KKEEP    1024
#define HIDDEN   256
#define JT       8
#define NTILE    (HIDDEN/JT)
#define STR      12   // LDS row stride (floats): 48B rows -> 16B aligned, 8 bank-groups

// Kernel A: one block per graph. Per-node projections A=h@W1a+b1, B=h@W1b
// in 8-wide hidden tiles held in LDS, consumed immediately by the graph's
// 4096 edges.
// amdgpu_waves_per_eu(4,4): R3/R4 showed launch_bounds' min-occupancy hint is
// ignored by RA (it targeted 8 waves/EU = 64 VGPR and spilled hreg -> ~800MB
// scratch traffic). Capping MAX waves/EU at 4 makes the budget 128 VGPR.
__global__ __attribute__((amdgpu_flat_work_group_size(1024, 1024),
                          amdgpu_waves_per_eu(4, 4)))
void scores_kernel(
    const float* __restrict__ h, const float* __restrict__ W1,
    const float* __restrict__ b1, const float* __restrict__ W2,
    const float* __restrict__ b2, const int* __restrict__ edge0,
    const int* __restrict__ edge1, float* __restrict__ sc_out)
{
  __shared__ __align__(16) float At[NPER * STR];
  __shared__ __align__(16) float Bt[NPER * STR];
  const int t = threadIdx.x;
  const int b = blockIdx.x;
  const int mat = t >> 9;          // 0: A-projection waves, 1: B-projection waves
  const int n   = t & (NPER - 1);

  // h row for this thread's node, kept in registers for all 32 tiles.
  const float4* hrow = (const float4*)(h + ((size_t)b * NPER + n) * DDIM);
  float hreg[DDIM];
#pragma unroll
  for (int i = 0; i < 16; ++i) {
    float4 v = hrow[i];
    // Pin: defining op is opaque asm -> no remat of the global loads.
    asm volatile("" : "+v"(v.x), "+v"(v.y), "+v"(v.z), "+v"(v.w));
    hreg[4*i+0] = v.x; hreg[4*i+1] = v.y; hreg[4*i+2] = v.z; hreg[4*i+3] = v.w;
  }

  // this thread's 4 edges (local node ids), score accumulators in registers
  int er[4], ec[4];
  float eacc[4];
#pragma unroll
  for (int i = 0; i < 4; ++i) {
    const size_t e = (size_t)b * EPER + t + i * 1024;
    er[i] = edge0[e] & (NPER - 1);
    ec[i] = edge1[e] & (NPER - 1);
    eacc[i] = 0.f;
  }

  const int matu = __builtin_amdgcn_readfirstlane(mat);   // wave-uniform -> s_loads for W1
  const float* __restrict__ W1m = W1 + (size_t)matu * 64 * HIDDEN;
  float* const dst = (matu ? Bt : At) + n * STR;

  for (int jt = 0; jt < NTILE; ++jt) {
    const int j0 = jt * JT;
    float a8[JT];
#pragma unroll
    for (int jj = 0; jj < JT; ++jj) a8[jj] = matu ? 0.f : b1[j0 + jj];
#pragma unroll
    for (int d = 0; d < DDIM; ++d) {
      const float hval = hreg[d];
#pragma unroll
      for (int jj = 0; jj < JT; ++jj)
        a8[jj] = fmaf(hval, W1m[d * HIDDEN + j0 + jj], a8[jj]);
    }
    {
      float4 s0 = {a8[0], a8[1], a8[2], a8[3]};
      float4 s1 = {a8[4], a8[5], a8[6], a8[7]};
      ((float4*)dst)[0] = s0;
      ((float4*)dst)[1] = s1;
    }
    __syncthreads();

    float w2r[JT];
#pragma unroll
    for (int jj = 0; jj < JT; ++jj) w2r[jj] = W2[j0 + jj];   // uniform -> s_load

#pragma unroll
    for (int i = 0; i < 4; ++i) {
      const float4* ar = (const float4*)(At + er[i] * STR);
      const float4* br = (const float4*)(Bt + ec[i] * STR);
      const float4 a0 = ar[0], a1 = ar[1];
      const float4 c0 = br[0], c1 = br[1];
      float p = 0.f;
      p = fmaf(fmaxf(a0.x + c0.x, 0.f), w2r[0], p);
      p = fmaf(fmaxf(a0.y + c0.y, 0.f), w2r[1], p);
      p = fmaf(fmaxf(a0.z + c0.z, 0.f), w2r[2], p);
      p = fmaf(fmaxf(a0.w + c0.w, 0.f), w2r[3], p);
      p = fmaf(fmaxf(a1.x + c1.x, 0.f), w2r[4], p);
      p = fmaf(fmaxf(a1.y + c1.y, 0.f), w2r[5], p);
      p = fmaf(fmaxf(a1.z + c1.z, 0.f), w2r[6], p);
      p = fmaf(fmaxf(a1.w + c1.w, 0.f), w2r[7], p);
      eacc[i] += p;
    }
    __syncthreads();   // protect LDS tiles before next tile's writes
  }

  const float b2v = b2[0];
#pragma unroll
  for (int i = 0; i < 4; ++i)
    sc_out[(size_t)b * EPER + t + i * 1024] = eacc[i] + b2v;
}

// Kernel B: per-graph bitonic sort of (score desc, idx asc) packed u64 keys,
// write causal/spurious edge weights, build node mask from kept edges,
// masked-sum h -> causal_rep. One block per graph.  (R1-verified version.)
__global__ __launch_bounds__(1024) void sort_kernel(
    const float* __restrict__ sc, const int* __restrict__ edge0,
    const int* __restrict__ edge1, const float* __restrict__ h,
    float* __restrict__ out_rep, float* __restrict__ out_cw,
    float* __restrict__ out_sw)
{
  __shared__ unsigned long long keys[EPER];  // 32 KB
  __shared__ int mask[NPER];                 // 2 KB
  __shared__ float red[16 * 64];             // 4 KB
  const int t = threadIdx.x;
  const int b = blockIdx.x;

  if (t < NPER) mask[t] = 0;

  // build keys: ascending u64 order == (score desc, edge idx asc)
#pragma unroll
  for (int i = 0; i < 4; ++i) {
    const int e = t + i * 1024;
    const float s = sc[(size_t)b * EPER + e];
    unsigned u  = __float_as_uint(s);
    unsigned fk = (u & 0x80000000u) ? ~u : (u | 0x80000000u);  // ascending-orderable
    unsigned dk = ~fk;                                          // descending
    keys[e] = ((unsigned long long)dk << 32) | (unsigned)e;
  }

  for (int k = 2; k <= EPER; k <<= 1) {
    for (int j = k >> 1; j > 0; j >>= 1) {
      __syncthreads();
#pragma unroll
      for (int i = 0; i < 4; ++i) {
        const int p = t + i * 1024;
        const int l = p ^ j;
        if (l > p) {
          const unsigned long long a = keys[p], c = keys[l];
          const bool up = ((p & k) == 0);
          if (up ? (a > c) : (a < c)) { keys[p] = c; keys[l] = a; }
        }
      }
    }
  }
  __syncthreads();

  // sorted outputs: positions [0,K) -> causal weights, [K,E) -> -score
#pragma unroll
  for (int i = 0; i < 4; ++i) {
    const int p = t + i * 1024;
    const unsigned long long key = keys[p];
    const unsigned fk = ~(unsigned)(key >> 32);
    const unsigned u  = (fk & 0x80000000u) ? (fk & 0x7fffffffu) : ~fk;  // exact bits back
    const float s = __uint_as_float(u);
    if (p < KKEEP) out_cw[(size_t)b * KKEEP + p] = s;
    else           out_sw[(size_t)b * (EPER - KKEEP) + (p - KKEEP)] = -s;
  }

  // node mask from kept edges (blockDim == KKEEP, so thread t owns position t)
  {
    const int e = (int)(keys[t] & 0xffffffffu);
    const size_t eg = (size_t)b * EPER + e;
    mask[edge0[eg] & (NPER - 1)] = 1;   // same-value LDS races are benign
    mask[edge1[eg] & (NPER - 1)] = 1;
  }
  __syncthreads();

  // masked segment sum: lanes = dims (coalesced h reads), 16 node-groups
  {
    const int d = t & 63, g = t >> 6;
    float s = 0.f;
    for (int nn = g; nn < NPER; nn += 16)
      if (mask[nn]) s += h[((size_t)b * NPER + nn) * DDIM + d];
    red[g * 64 + d] = s;
  }
  __syncthreads();
  if (t < 64) {
    float tot = 0.f;
#pragma unroll
    for (int g = 0; g < 16; ++g) tot += red[g * 64 + t];
    out_rep[(size_t)b * DDIM + t] = tot;
  }
}

extern "C" void kernel_launch(void* const* d_in, const int* in_sizes, int n_in,
                              void* d_out, int out_size, void* d_ws, size_t ws_size,
                              hipStream_t stream) {
  const float* h    = (const float*)d_in[0];
  const float* W1   = (const float*)d_in[1];
  const float* b1   = (const float*)d_in[2];
  const float* W2   = (const float*)d_in[3];
  const float* b2   = (const float*)d_in[4];
  const int*   eidx = (const int*)d_in[5];
  const int* edge0 = eidx;
  const int* edge1 = eidx + (size_t)B_GRAPHS * EPER;

  float* sc = (float*)d_ws;                 // 4 MB scratch for scores

  float* out     = (float*)d_out;
  float* out_rep = out;                                   // 256*64
  float* out_cw  = out + B_GRAPHS * DDIM;                 // 256*1024
  float* out_sw  = out_cw + (size_t)B_GRAPHS * KKEEP;     // 256*3072

  scores_kernel<<<B_GRAPHS, 1024, 0, stream>>>(h, W1, b1, W2, b2, edge0, edge1, sc);
  sort_kernel<<<B_GRAPHS, 1024, 0, stream>>>(sc, edge0, edge1, h, out_rep, out_cw, out_sw);
}

// Round 6
// 359.363 us; speedup vs baseline: 1.2814x; 1.2814x over previous
//
#include <hip/hip_runtime.h>
#include <stdint.h>

#define B_GRAPHS 256
#define NPER     512
#define EPER     4096
#define DDIM     64
#define KKEEP    1024
#define HIDDEN   256
#define JT       8
#define NTILE    (HIDDEN/JT)
#define STR      12   // LDS row stride (floats): 48B rows -> 16B aligned, 8 bank-groups

// Kernel A: one block per graph. R3-R5 showed the RA pins 1024-thread kernels
// to 64 arch VGPRs regardless of launch_bounds/waves_per_eu, spilling the old
// hreg[64] (~800MB scratch traffic). Restructure: each node's h-row is SPLIT
// across two threads (half = t>>9, 32 dims each); partial A/B projections are
// combined through the At/Bt LDS tiles. Live set ~66 regs -> fits the 64-VGPR
// budget with negligible spill. Same total FMA count.
__global__ __launch_bounds__(1024) void scores_kernel(
    const float* __restrict__ h, const float* __restrict__ W1,
    const float* __restrict__ b1, const float* __restrict__ W2,
    const float* __restrict__ b2, const int* __restrict__ edge0,
    const int* __restrict__ edge1, float* __restrict__ sc_out)
{
  __shared__ __align__(16) float At[NPER * STR];
  __shared__ __align__(16) float Bt[NPER * STR];
  const int t = threadIdx.x;
  const int b = blockIdx.x;
  const int half = __builtin_amdgcn_readfirstlane(t >> 9);  // wave-uniform
  const int n    = t & (NPER - 1);

  // 32 floats of h: h[n][half*32 .. half*32+32), pinned against remat.
  float hreg[32];
  const float4* hrow = (const float4*)(h + ((size_t)b * NPER + n) * DDIM + half * 32);
#pragma unroll
  for (int i = 0; i < 8; ++i) {
    float4 v = hrow[i];
    asm volatile("" : "+v"(v.x), "+v"(v.y), "+v"(v.z), "+v"(v.w));
    hreg[4*i+0] = v.x; hreg[4*i+1] = v.y; hreg[4*i+2] = v.z; hreg[4*i+3] = v.w;
  }

  // 4 edges per thread, node ids packed to save registers
  int epk[4];
  float eacc[4];
#pragma unroll
  for (int i = 0; i < 4; ++i) {
    const size_t e = (size_t)b * EPER + t + i * 1024;
    epk[i] = (edge0[e] & (NPER - 1)) | ((edge1[e] & (NPER - 1)) << 16);
    eacc[i] = 0.f;
  }

  // W1 row bases (wave-uniform -> s_loads).
  // A (h[row]) uses W1 rows [half*32, half*32+32); B (h[col]) rows 64 + same.
  const float* __restrict__ W1a = W1 + (size_t)(half * 32) * HIDDEN;
  const float* __restrict__ W1b = W1 + (size_t)(64 + half * 32) * HIDDEN;

  for (int jt = 0; jt < NTILE; ++jt) {
    const int j0 = jt * JT;

    // partial projections over this thread's 32 dims
    float pa[JT], pb[JT];
#pragma unroll
    for (int jj = 0; jj < JT; ++jj) {
      pa[jj] = (half == 0) ? b1[j0 + jj] : 0.f;
      pb[jj] = 0.f;
    }
#pragma unroll
    for (int d = 0; d < 32; ++d) {
      const float hv = hreg[d];
#pragma unroll
      for (int jj = 0; jj < JT; ++jj)
        pa[jj] = fmaf(hv, W1a[d * HIDDEN + j0 + jj], pa[jj]);
#pragma unroll
      for (int jj = 0; jj < JT; ++jj)
        pb[jj] = fmaf(hv, W1b[d * HIDDEN + j0 + jj], pb[jj]);
    }

    // phase 1: half1 stages its A-partial in At, half0 stages B-partial in Bt
    if (half) {
      float4 s0 = {pa[0], pa[1], pa[2], pa[3]};
      float4 s1 = {pa[4], pa[5], pa[6], pa[7]};
      ((float4*)(At + n * STR))[0] = s0;
      ((float4*)(At + n * STR))[1] = s1;
    } else {
      float4 s0 = {pb[0], pb[1], pb[2], pb[3]};
      float4 s1 = {pb[4], pb[5], pb[6], pb[7]};
      ((float4*)(Bt + n * STR))[0] = s0;
      ((float4*)(Bt + n * STR))[1] = s1;
    }
    __syncthreads();

    // phase 2: the other half adds its partial and finalizes the row
    if (half == 0) {
      const float4 o0 = ((const float4*)(At + n * STR))[0];
      const float4 o1 = ((const float4*)(At + n * STR))[1];
      float4 s0 = {pa[0] + o0.x, pa[1] + o0.y, pa[2] + o0.z, pa[3] + o0.w};
      float4 s1 = {pa[4] + o1.x, pa[5] + o1.y, pa[6] + o1.z, pa[7] + o1.w};
      ((float4*)(At + n * STR))[0] = s0;
      ((float4*)(At + n * STR))[1] = s1;
    } else {
      const float4 o0 = ((const float4*)(Bt + n * STR))[0];
      const float4 o1 = ((const float4*)(Bt + n * STR))[1];
      float4 s0 = {pb[0] + o0.x, pb[1] + o0.y, pb[2] + o0.z, pb[3] + o0.w};
      float4 s1 = {pb[4] + o1.x, pb[5] + o1.y, pb[6] + o1.z, pb[7] + o1.w};
      ((float4*)(Bt + n * STR))[0] = s0;
      ((float4*)(Bt + n * STR))[1] = s1;
    }
    __syncthreads();

    // edge gather
    float w2r[JT];
#pragma unroll
    for (int jj = 0; jj < JT; ++jj) w2r[jj] = W2[j0 + jj];   // uniform -> s_load

#pragma unroll
    for (int i = 0; i < 4; ++i) {
      const int er = epk[i] & 0xffff;
      const int ec = ((unsigned)epk[i]) >> 16;
      const float4* ar = (const float4*)(At + er * STR);
      const float4* br = (const float4*)(Bt + ec * STR);
      const float4 a0 = ar[0], a1 = ar[1];
      const float4 c0 = br[0], c1 = br[1];
      float p = 0.f;
      p = fmaf(fmaxf(a0.x + c0.x, 0.f), w2r[0], p);
      p = fmaf(fmaxf(a0.y + c0.y, 0.f), w2r[1], p);
      p = fmaf(fmaxf(a0.z + c0.z, 0.f), w2r[2], p);
      p = fmaf(fmaxf(a0.w + c0.w, 0.f), w2r[3], p);
      p = fmaf(fmaxf(a1.x + c1.x, 0.f), w2r[4], p);
      p = fmaf(fmaxf(a1.y + c1.y, 0.f), w2r[5], p);
      p = fmaf(fmaxf(a1.z + c1.z, 0.f), w2r[6], p);
      p = fmaf(fmaxf(a1.w + c1.w, 0.f), w2r[7], p);
      eacc[i] += p;
    }
    __syncthreads();   // tiles consumed before next tile's staging writes
  }

  const float b2v = b2[0];
#pragma unroll
  for (int i = 0; i < 4; ++i)
    sc_out[(size_t)b * EPER + t + i * 1024] = eacc[i] + b2v;
}

// Kernel B: per-graph bitonic sort of (score desc, idx asc) packed u64 keys,
// write causal/spurious edge weights, build node mask from kept edges,
// masked-sum h -> causal_rep. One block per graph.  (R1-verified version.)
__global__ __launch_bounds__(1024) void sort_kernel(
    const float* __restrict__ sc, const int* __restrict__ edge0,
    const int* __restrict__ edge1, const float* __restrict__ h,
    float* __restrict__ out_rep, float* __restrict__ out_cw,
    float* __restrict__ out_sw)
{
  __shared__ unsigned long long keys[EPER];  // 32 KB
  __shared__ int mask[NPER];                 // 2 KB
  __shared__ float red[16 * 64];             // 4 KB
  const int t = threadIdx.x;
  const int b = blockIdx.x;

  if (t < NPER) mask[t] = 0;

  // build keys: ascending u64 order == (score desc, edge idx asc)
#pragma unroll
  for (int i = 0; i < 4; ++i) {
    const int e = t + i * 1024;
    const float s = sc[(size_t)b * EPER + e];
    unsigned u  = __float_as_uint(s);
    unsigned fk = (u & 0x80000000u) ? ~u : (u | 0x80000000u);  // ascending-orderable
    unsigned dk = ~fk;                                          // descending
    keys[e] = ((unsigned long long)dk << 32) | (unsigned)e;
  }

  for (int k = 2; k <= EPER; k <<= 1) {
    for (int j = k >> 1; j > 0; j >>= 1) {
      __syncthreads();
#pragma unroll
      for (int i = 0; i < 4; ++i) {
        const int p = t + i * 1024;
        const int l = p ^ j;
        if (l > p) {
          const unsigned long long a = keys[p], c = keys[l];
          const bool up = ((p & k) == 0);
          if (up ? (a > c) : (a < c)) { keys[p] = c; keys[l] = a; }
        }
      }
    }
  }
  __syncthreads();

  // sorted outputs: positions [0,K) -> causal weights, [K,E) -> -score
#pragma unroll
  for (int i = 0; i < 4; ++i) {
    const int p = t + i * 1024;
    const unsigned long long key = keys[p];
    const unsigned fk = ~(unsigned)(key >> 32);
    const unsigned u  = (fk & 0x80000000u) ? (fk & 0x7fffffffu) : ~fk;  // exact bits back
    const float s = __uint_as_float(u);
    if (p < KKEEP) out_cw[(size_t)b * KKEEP + p] = s;
    else           out_sw[(size_t)b * (EPER - KKEEP) + (p - KKEEP)] = -s;
  }

  // node mask from kept edges (blockDim == KKEEP, so thread t owns position t)
  {
    const int e = (int)(keys[t] & 0xffffffffu);
    const size_t eg = (size_t)b * EPER + e;
    mask[edge0[eg] & (NPER - 1)] = 1;   // same-value LDS races are benign
    mask[edge1[eg] & (NPER - 1)] = 1;
  }
  __syncthreads();

  // masked segment sum: lanes = dims (coalesced h reads), 16 node-groups
  {
    const int d = t & 63, g = t >> 6;
    float s = 0.f;
    for (int nn = g; nn < NPER; nn += 16)
      if (mask[nn]) s += h[((size_t)b * NPER + nn) * DDIM + d];
    red[g * 64 + d] = s;
  }
  __syncthreads();
  if (t < 64) {
    float tot = 0.f;
#pragma unroll
    for (int g = 0; g < 16; ++g) tot += red[g * 64 + t];
    out_rep[(size_t)b * DDIM + t] = tot;
  }
}

extern "C" void kernel_launch(void* const* d_in, const int* in_sizes, int n_in,
                              void* d_out, int out_size, void* d_ws, size_t ws_size,
                              hipStream_t stream) {
  const float* h    = (const float*)d_in[0];
  const float* W1   = (const float*)d_in[1];
  const float* b1   = (const float*)d_in[2];
  const float* W2   = (const float*)d_in[3];
  const float* b2   = (const float*)d_in[4];
  const int*   eidx = (const int*)d_in[5];
  const int* edge0 = eidx;
  const int* edge1 = eidx + (size_t)B_GRAPHS * EPER;

  float* sc = (float*)d_ws;                 // 4 MB scratch for scores

  float* out     = (float*)d_out;
  float* out_rep = out;                                   // 256*64
  float* out_cw  = out + B_GRAPHS * DDIM;                 // 256*1024
  float* out_sw  = out_cw + (size_t)B_GRAPHS * KKEEP;     // 256*3072

  scores_kernel<<<B_GRAPHS, 1024, 0, stream>>>(h, W1, b1, W2, b2, edge0, edge1, sc);
  sort_kernel<<<B_GRAPHS, 1024, 0, stream>>>(sc, edge0, edge1, h, out_rep, out_cw, out_sw);
}